// Round 1
// baseline (269.941 us; speedup 1.0000x reference)
//
#include <hip/hip_runtime.h>
#include <math.h>

// EdgeConv: B=16, N=8192, K=20, D=64
// h[b,n,k,o] = Y1[b,idx,o] + (Y2-Y1)[b,n,o];  out = GELU(LN(max_k h))
#define B_ 16
#define N_ 8192
#define K_ 20
#define D_ 64
#define NPTS (B_ * N_)   // 131072

// ---------------- Kernel 1: projections ----------------
// Y1[p][o]  = sum_d x[p][d] * W[o][d]
// Bs[p][o]  = sum_d x[p][d] * (W[o][64+d] - W[o][d])   (= Y2 - Y1)
__global__ __launch_bounds__(256) void proj_kernel(const float* __restrict__ x,
                                                   const float* __restrict__ W,
                                                   float* __restrict__ Y1,
                                                   float* __restrict__ Bs) {
    __shared__ float Wt1[64 * 64];  // Wt1[d][o] = W[o][d]
    __shared__ float Wtb[64 * 64];  // Wtb[d][o] = W[o][64+d] - W[o][d]
    const int tid = threadIdx.x;
    for (int i = tid; i < 64 * 64; i += 256) {
        int o = i >> 6, d = i & 63;
        float w1 = W[o * 128 + d];
        float w2 = W[o * 128 + 64 + d];
        Wt1[d * 64 + o] = w1;
        Wtb[d * 64 + o] = w2 - w1;
    }
    __syncthreads();

    const int lane = tid & 63;
    const int wave = tid >> 6;
    // 64 rows per block, one row per wave per iteration
    const int r0 = blockIdx.x * 64;
    for (int it = 0; it < 16; ++it) {
        const int r = r0 + it * 4 + wave;
        const float xv = x[r * 64 + lane];
        float acc1 = 0.f, accb = 0.f;
#pragma unroll
        for (int d = 0; d < 64; ++d) {
            float xd = __shfl(xv, d, 64);
            acc1 = fmaf(xd, Wt1[d * 64 + lane], acc1);  // lane stride 1 -> 2-way bank alias (free)
            accb = fmaf(xd, Wtb[d * 64 + lane], accb);
        }
        Y1[r * 64 + lane] = acc1;
        Bs[r * 64 + lane] = accb;
    }
}

// ---------------- Kernel 2: gather + max + LN + GELU ----------------
__global__ __launch_bounds__(256) void gather_kernel(const float* __restrict__ Y1,
                                                     const float* __restrict__ Bs,
                                                     const int* __restrict__ ind,
                                                     const float* __restrict__ gamma,
                                                     const float* __restrict__ beta,
                                                     float* __restrict__ out) {
    const int lane = threadIdx.x & 63;
    const int wave = threadIdx.x >> 6;
    const int p = blockIdx.x * 4 + wave;       // global point index = b*N + n
    const int b = p >> 13;                     // p / 8192
    const int bbase = b * N_ * 64;             // batch base into Y1 (fits int: max 8.4M)

    // load all 20 neighbor indices first (wave-uniform addresses)
    int idxs[K_];
#pragma unroll
    for (int k = 0; k < K_; ++k) idxs[k] = ind[p * K_ + k];

    // gather + running max; 20 coalesced 256B row loads, L2-resident table
    float m = -INFINITY;
#pragma unroll
    for (int k = 0; k < K_; ++k) {
        float v = Y1[bbase + idxs[k] * 64 + lane];
        m = fmaxf(m, v);
    }
    float h = m + Bs[p * 64 + lane];

    // LayerNorm across the 64 lanes (D == wave width)
    float s = h;
#pragma unroll
    for (int off = 32; off >= 1; off >>= 1) s += __shfl_xor(s, off, 64);
    const float mu = s * (1.0f / 64.0f);
    const float dv = h - mu;
    float v2 = dv * dv;
#pragma unroll
    for (int off = 32; off >= 1; off >>= 1) v2 += __shfl_xor(v2, off, 64);
    const float var = v2 * (1.0f / 64.0f);
    const float hn = dv * rsqrtf(var + 1e-5f) * gamma[lane] + beta[lane];

    // exact GELU: 0.5*x*(1+erf(x/sqrt(2)))
    const float g = 0.5f * hn * (1.0f + erff(hn * 0.70710678118654752f));
    out[p * 64 + lane] = g;
}

extern "C" void kernel_launch(void* const* d_in, const int* in_sizes, int n_in,
                              void* d_out, int out_size, void* d_ws, size_t ws_size,
                              hipStream_t stream) {
    const float* x     = (const float*)d_in[0];
    const int*   ind   = (const int*)d_in[1];
    const float* W     = (const float*)d_in[2];
    const float* gamma = (const float*)d_in[3];
    const float* beta  = (const float*)d_in[4];
    float* out = (float*)d_out;

    float* Y1 = (float*)d_ws;                      // 131072*64 floats = 33.5 MB
    float* Bs = Y1 + (size_t)NPTS * 64;            // another 33.5 MB

    proj_kernel<<<NPTS / 64, 256, 0, stream>>>(x, W, Y1, Bs);
    gather_kernel<<<NPTS / 4, 256, 0, stream>>>(Y1, Bs, ind, gamma, beta, out);
}

// Round 2
// 206.167 us; speedup vs baseline: 1.3093x; 1.3093x over previous
//
#include <hip/hip_runtime.h>
#include <math.h>

// EdgeConv: B=16, N=8192, K=20, D=64
// h[b,n,k,o] = Y1[b,idx,o] + (Y2-Y1)[b,n,o];  out = GELU(LN(max_k h))
#define B_ 16
#define N_ 8192
#define K_ 20
#define D_ 64
#define NPTS (B_ * N_)   // 131072

typedef __attribute__((ext_vector_type(4))) float f4;

// ---------------- Kernel 1: projections (register-blocked GEMM) ----------------
// Out cols o in [0,128): o<64 -> Y1[o] = sum_k x[k]*W[o][k]
//                        o>=64 -> Bs[o-64] = sum_k x[k]*(W[o-64][64+k]-W[o-64][k])
// Block: 256 threads, 64 rows. Thread (t&31) -> 4 output cols, (t>>5) -> 8 rows.
__global__ __launch_bounds__(256) void proj_kernel(const float* __restrict__ x,
                                                   const float* __restrict__ W,
                                                   float* __restrict__ Y1,
                                                   float* __restrict__ Bs) {
    __shared__ float Wt[64 * 128];   // Wt[k*128 + o]
    __shared__ float xs[64 * 68];    // xs[k*68 + r], pad 68 keeps 16B align (68*4=272)
    const int t = threadIdx.x;
    const int r0 = blockIdx.x * 64;

    // stage W transformed: 8192 elems, 32 per thread
    for (int i = t; i < 64 * 128; i += 256) {
        int k = i >> 7, o = i & 127;
        float w;
        if (o < 64) {
            w = W[o * 128 + k];
        } else {
            int oo = o - 64;
            w = W[oo * 128 + 64 + k] - W[oo * 128 + k];
        }
        Wt[i] = w;
    }
    // stage x transposed: xs[k][r] = x[r0+r][k]
    for (int i = t; i < 64 * 64; i += 256) {
        int r = i >> 6, k = i & 63;
        xs[k * 68 + r] = x[(r0 + r) * 64 + k];
    }
    __syncthreads();

    const int o4 = (t & 31) * 4;   // output col base
    const int rb = (t >> 5) * 8;   // row base
    f4 acc0 = 0.f, acc1 = 0.f, acc2 = 0.f, acc3 = 0.f;
    f4 acc4 = 0.f, acc5 = 0.f, acc6 = 0.f, acc7 = 0.f;

#pragma unroll 4
    for (int k = 0; k < 64; ++k) {
        f4 w  = *(const f4*)&Wt[k * 128 + o4];   // 32 distinct f4 per wave
        f4 xa = *(const f4*)&xs[k * 68 + rb];    // wave-broadcast (2 addrs/wave)
        f4 xb = *(const f4*)&xs[k * 68 + rb + 4];
        acc0 += xa.x * w;  acc1 += xa.y * w;  acc2 += xa.z * w;  acc3 += xa.w * w;
        acc4 += xb.x * w;  acc5 += xb.y * w;  acc6 += xb.z * w;  acc7 += xb.w * w;
    }

    float* dst;
    int oc;
    if (o4 < 64) { dst = Y1; oc = o4; } else { dst = Bs; oc = o4 - 64; }
    f4* d0 = (f4*)&dst[(size_t)(r0 + rb) * 64 + oc];
    const int strd = 64 / 4;   // f4 elements per row
    d0[0 * strd] = acc0;  d0[1 * strd] = acc1;  d0[2 * strd] = acc2;  d0[3 * strd] = acc3;
    d0[4 * strd] = acc4;  d0[5 * strd] = acc5;  d0[6 * strd] = acc6;  d0[7 * strd] = acc7;
}

// ---------------- Kernel 2: gather + max + LN + GELU ----------------
// 4 points per wave: 16 lanes/point, each lane holds 4 channels (f4).
__global__ __launch_bounds__(256) void gather_kernel(const float* __restrict__ Y1,
                                                     const float* __restrict__ Bs,
                                                     const int* __restrict__ ind,
                                                     const float* __restrict__ gamma,
                                                     const float* __restrict__ beta,
                                                     float* __restrict__ out) {
    const int lane = threadIdx.x & 63;
    const int wave = threadIdx.x >> 6;
    const int sub = lane & 15;          // channel group within point
    const int q = lane >> 4;            // point within wave
    const int p = blockIdx.x * 16 + wave * 4 + q;   // global point
    const int b = p >> 13;
    const size_t bbase = (size_t)b * N_ * 64;

    int idxs[K_];
#pragma unroll
    for (int k = 0; k < K_; ++k) idxs[k] = ind[p * K_ + k];

    f4 m = (f4)(-INFINITY);
#pragma unroll
    for (int k = 0; k < K_; ++k) {
        f4 v = *(const f4*)&Y1[bbase + (size_t)idxs[k] * 64 + sub * 4];
        m.x = fmaxf(m.x, v.x); m.y = fmaxf(m.y, v.y);
        m.z = fmaxf(m.z, v.z); m.w = fmaxf(m.w, v.w);
    }
    f4 base = __builtin_nontemporal_load((const f4*)&Bs[(size_t)p * 64 + sub * 4]);
    f4 h = m + base;

    // LayerNorm over 64 channels = 4 comps x 16 lanes
    float s = h.x + h.y + h.z + h.w;
#pragma unroll
    for (int off = 8; off >= 1; off >>= 1) s += __shfl_xor(s, off, 64);
    const float mu = s * (1.0f / 64.0f);
    f4 dv = h - mu;
    float v2 = dv.x * dv.x + dv.y * dv.y + dv.z * dv.z + dv.w * dv.w;
#pragma unroll
    for (int off = 8; off >= 1; off >>= 1) v2 += __shfl_xor(v2, off, 64);
    const float rstd = rsqrtf(v2 * (1.0f / 64.0f) + 1e-5f);

    f4 g4 = *(const f4*)&gamma[sub * 4];
    f4 b4 = *(const f4*)&beta[sub * 4];
    f4 hn = dv * rstd * g4 + b4;

    f4 r;
    r.x = 0.5f * hn.x * (1.0f + erff(hn.x * 0.70710678f));
    r.y = 0.5f * hn.y * (1.0f + erff(hn.y * 0.70710678f));
    r.z = 0.5f * hn.z * (1.0f + erff(hn.z * 0.70710678f));
    r.w = 0.5f * hn.w * (1.0f + erff(hn.w * 0.70710678f));
    __builtin_nontemporal_store(r, (f4*)&out[(size_t)p * 64 + sub * 4]);
}

extern "C" void kernel_launch(void* const* d_in, const int* in_sizes, int n_in,
                              void* d_out, int out_size, void* d_ws, size_t ws_size,
                              hipStream_t stream) {
    const float* x     = (const float*)d_in[0];
    const int*   ind   = (const int*)d_in[1];
    const float* W     = (const float*)d_in[2];
    const float* gamma = (const float*)d_in[3];
    const float* beta  = (const float*)d_in[4];
    float* out = (float*)d_out;

    float* Y1 = (float*)d_ws;                      // 131072*64 floats = 33.5 MB
    float* Bs = Y1 + (size_t)NPTS * 64;            // another 33.5 MB

    proj_kernel<<<NPTS / 64, 256, 0, stream>>>(x, W, Y1, Bs);
    gather_kernel<<<NPTS / 16, 256, 0, stream>>>(Y1, Bs, ind, gamma, beta, out);
}

// Round 3
// 175.906 us; speedup vs baseline: 1.5346x; 1.1720x over previous
//
#include <hip/hip_runtime.h>
#include <hip/hip_bf16.h>
#include <math.h>

// EdgeConv: B=16, N=8192, K=20, D=64
// h[b,n,k,o] = Y1[b,idx,o] + (Y2-Y1)[b,n,o];  out = GELU(LN(max_k h))
#define B_ 16
#define N_ 8192
#define K_ 20
#define D_ 64
#define NPTS (B_ * N_)   // 131072

typedef __attribute__((ext_vector_type(4))) float f4;

struct bf4 { __hip_bfloat16 a, b, c, d; };   // 8 bytes

// ---------------- Kernel 1: projections (register-blocked GEMM) ----------------
// Y1 (bf16): o<64  -> sum_k x[k]*W[o][k]
// Bs (f32):  o>=64 -> sum_k x[k]*(W[o-64][64+k]-W[o-64][k])
__global__ __launch_bounds__(256) void proj_kernel(const float* __restrict__ x,
                                                   const float* __restrict__ W,
                                                   __hip_bfloat16* __restrict__ Y1,
                                                   float* __restrict__ Bs) {
    __shared__ float Wt[64 * 132];   // Wt[k*132 + o], pad 132 keeps 16B align + breaks conflicts
    __shared__ float xs[64 * 68];    // xs[k*68 + r]
    const int t = threadIdx.x;
    const int r0 = blockIdx.x * 64;

    // COALESCED W staging: lanes vary k (contiguous 256B reads per wave).
    // LDS write stride 132 -> 8-way bank conflict, negligible (~350 cyc/wave).
    for (int i = t; i < 64 * 128; i += 256) {
        int o = i >> 6, k = i & 63;
        float w;
        if (o < 64) {
            w = W[o * 128 + k];
        } else {
            int oo = o - 64;
            w = W[oo * 128 + 64 + k] - W[oo * 128 + k];
        }
        Wt[k * 132 + o] = w;
    }
    // x staging: coalesced global read (lanes vary k)
    for (int i = t; i < 64 * 64; i += 256) {
        int r = i >> 6, k = i & 63;
        xs[k * 68 + r] = x[(r0 + r) * 64 + k];
    }
    __syncthreads();

    const int o4 = (t & 31) * 4;   // output col base (0..124)
    const int rb = (t >> 5) * 8;   // row base (0..56)
    f4 acc0 = 0.f, acc1 = 0.f, acc2 = 0.f, acc3 = 0.f;
    f4 acc4 = 0.f, acc5 = 0.f, acc6 = 0.f, acc7 = 0.f;

#pragma unroll 4
    for (int k = 0; k < 64; ++k) {
        f4 w  = *(const f4*)&Wt[k * 132 + o4];   // conflict-free (contiguous per half-wave)
        f4 xa = *(const f4*)&xs[k * 68 + rb];    // wave-broadcast
        f4 xb = *(const f4*)&xs[k * 68 + rb + 4];
        acc0 += xa.x * w;  acc1 += xa.y * w;  acc2 += xa.z * w;  acc3 += xa.w * w;
        acc4 += xb.x * w;  acc5 += xb.y * w;  acc6 += xb.z * w;  acc7 += xb.w * w;
    }

    if (o4 < 64) {
        // Y1 path: bf16, 16 lanes x 8B = 128B per row
        f4 a[8] = {acc0, acc1, acc2, acc3, acc4, acc5, acc6, acc7};
#pragma unroll
        for (int j = 0; j < 8; ++j) {
            bf4 u{__float2bfloat16(a[j].x), __float2bfloat16(a[j].y),
                  __float2bfloat16(a[j].z), __float2bfloat16(a[j].w)};
            *(bf4*)&Y1[(size_t)(r0 + rb + j) * 64 + o4] = u;
        }
    } else {
        const int oc = o4 - 64;
        f4* d0 = (f4*)&Bs[(size_t)(r0 + rb) * 64 + oc];
        const int strd = 64 / 4;
        d0[0 * strd] = acc0;  d0[1 * strd] = acc1;  d0[2 * strd] = acc2;  d0[3 * strd] = acc3;
        d0[4 * strd] = acc4;  d0[5 * strd] = acc5;  d0[6 * strd] = acc6;  d0[7 * strd] = acc7;
    }
}

// ---------------- Kernel 2: gather + max + LN + GELU ----------------
// 4 points per wave: 16 lanes/point, each lane holds 4 channels.
__global__ __launch_bounds__(256) void gather_kernel(const __hip_bfloat16* __restrict__ Y1,
                                                     const float* __restrict__ Bs,
                                                     const int* __restrict__ ind,
                                                     const float* __restrict__ gamma,
                                                     const float* __restrict__ beta,
                                                     float* __restrict__ out) {
    const int lane = threadIdx.x & 63;
    const int wave = threadIdx.x >> 6;
    const int sub = lane & 15;          // channel group within point
    const int q = lane >> 4;            // point within wave
    const int p = blockIdx.x * 16 + wave * 4 + q;   // global point
    const int b = p >> 13;
    const int bbase = b * N_ * 64;      // element base into Y1 (max 8.4M, fits int)

    // 20 indices via 5 int4 loads (p*20*4B is 16B-aligned since 20%4==0)
    int idxs[K_];
    const int4* ip = (const int4*)&ind[p * K_];
#pragma unroll
    for (int v = 0; v < 5; ++v) {
        int4 iv = ip[v];
        idxs[v * 4 + 0] = iv.x; idxs[v * 4 + 1] = iv.y;
        idxs[v * 4 + 2] = iv.z; idxs[v * 4 + 3] = iv.w;
    }

    // bf16 gather: 16 lanes x 8B = 128B (one cache line) per row
    f4 m0 = (f4)(-INFINITY), m1 = (f4)(-INFINITY);
#pragma unroll
    for (int k = 0; k < K_; k += 2) {
        ushort4 v0 = *(const ushort4*)(Y1 + bbase + idxs[k] * 64 + sub * 4);
        ushort4 v1 = *(const ushort4*)(Y1 + bbase + idxs[k + 1] * 64 + sub * 4);
        f4 f0, f1;
        f0.x = __uint_as_float((unsigned)v0.x << 16); f0.y = __uint_as_float((unsigned)v0.y << 16);
        f0.z = __uint_as_float((unsigned)v0.z << 16); f0.w = __uint_as_float((unsigned)v0.w << 16);
        f1.x = __uint_as_float((unsigned)v1.x << 16); f1.y = __uint_as_float((unsigned)v1.y << 16);
        f1.z = __uint_as_float((unsigned)v1.z << 16); f1.w = __uint_as_float((unsigned)v1.w << 16);
        m0.x = fmaxf(m0.x, f0.x); m0.y = fmaxf(m0.y, f0.y);
        m0.z = fmaxf(m0.z, f0.z); m0.w = fmaxf(m0.w, f0.w);
        m1.x = fmaxf(m1.x, f1.x); m1.y = fmaxf(m1.y, f1.y);
        m1.z = fmaxf(m1.z, f1.z); m1.w = fmaxf(m1.w, f1.w);
    }
    f4 m;
    m.x = fmaxf(m0.x, m1.x); m.y = fmaxf(m0.y, m1.y);
    m.z = fmaxf(m0.z, m1.z); m.w = fmaxf(m0.w, m1.w);

    f4 base = __builtin_nontemporal_load((const f4*)&Bs[(size_t)p * 64 + sub * 4]);
    f4 h = m + base;

    // LayerNorm over 64 channels = 4 comps x 16 lanes
    float s = h.x + h.y + h.z + h.w;
#pragma unroll
    for (int off = 8; off >= 1; off >>= 1) s += __shfl_xor(s, off, 64);
    const float mu = s * (1.0f / 64.0f);
    f4 dv = h - mu;
    float v2 = dv.x * dv.x + dv.y * dv.y + dv.z * dv.z + dv.w * dv.w;
#pragma unroll
    for (int off = 8; off >= 1; off >>= 1) v2 += __shfl_xor(v2, off, 64);
    const float rstd = rsqrtf(v2 * (1.0f / 64.0f) + 1e-5f);

    f4 g4 = *(const f4*)&gamma[sub * 4];
    f4 b4 = *(const f4*)&beta[sub * 4];
    f4 hn = dv * rstd * g4 + b4;

    f4 r;
    r.x = 0.5f * hn.x * (1.0f + erff(hn.x * 0.70710678f));
    r.y = 0.5f * hn.y * (1.0f + erff(hn.y * 0.70710678f));
    r.z = 0.5f * hn.z * (1.0f + erff(hn.z * 0.70710678f));
    r.w = 0.5f * hn.w * (1.0f + erff(hn.w * 0.70710678f));
    __builtin_nontemporal_store(r, (f4*)&out[(size_t)p * 64 + sub * 4]);
}

extern "C" void kernel_launch(void* const* d_in, const int* in_sizes, int n_in,
                              void* d_out, int out_size, void* d_ws, size_t ws_size,
                              hipStream_t stream) {
    const float* x     = (const float*)d_in[0];
    const int*   ind   = (const int*)d_in[1];
    const float* W     = (const float*)d_in[2];
    const float* gamma = (const float*)d_in[3];
    const float* beta  = (const float*)d_in[4];
    float* out = (float*)d_out;

    float* Bs = (float*)d_ws;                                   // 33.5 MB fp32
    __hip_bfloat16* Y1 = (__hip_bfloat16*)((char*)d_ws + (size_t)NPTS * 64 * 4);  // 16.8 MB bf16

    proj_kernel<<<NPTS / 64, 256, 0, stream>>>(x, W, Y1, Bs);
    gather_kernel<<<NPTS / 16, 256, 0, stream>>>(Y1, Bs, ind, gamma, beta, out);
}

// Round 4
// 139.107 us; speedup vs baseline: 1.9405x; 1.2645x over previous
//
#include <hip/hip_runtime.h>
#include <math.h>

// EdgeConv: B=16, N=8192, K=20, D=64
// h[b,n,k,o] = Y1[b,idx,o] + Bs[b,n,o];  out = GELU(LN(max_k h))
// Y1[p][o] = sum_d x[p][d]*W[o][d]          (o<64)
// Bs[p][o] = sum_d x[p][d]*(W[o][64+d]-W[o][d])
#define B_ 16
#define N_ 8192
#define K_ 20
#define NPTS (B_ * N_)   // 131072

typedef __attribute__((ext_vector_type(4))) float f4;
typedef __attribute__((ext_vector_type(8))) short s8;   // 8 x bf16 MFMA fragment

__device__ __forceinline__ short f2bf(float f) {
    union { float f; unsigned u; } v; v.f = f;
    return (short)((v.u + 0x7FFFu + ((v.u >> 16) & 1u)) >> 16);   // RNE
}

__device__ __forceinline__ f4 bf4_to_f4(ushort4 v) {
    f4 r;
    r.x = __uint_as_float((unsigned)v.x << 16);
    r.y = __uint_as_float((unsigned)v.y << 16);
    r.z = __uint_as_float((unsigned)v.z << 16);
    r.w = __uint_as_float((unsigned)v.w << 16);
    return r;
}

// ---------------- Kernel 0: precompute combined W in bf16 (once per launch) ---
// Wg[j][d], j in [0,128): j<64 -> W[j][d] ; j>=64 -> W[j-64][64+d]-W[j-64][d]
__global__ __launch_bounds__(256) void prep_kernel(const float* __restrict__ W,
                                                   unsigned short* __restrict__ Wg) {
    const int i = blockIdx.x * 256 + threadIdx.x;   // 8192 elems
    const int j = i >> 6, d = i & 63;
    const float v = (j < 64) ? W[j * 128 + d]
                             : (W[(j - 64) * 128 + 64 + d] - W[(j - 64) * 128 + d]);
    Wg[i] = (unsigned short)f2bf(v);
}

// ---------------- Kernel 1: projections via MFMA ----------------
// Each wave: 16 rows x 128 cols, K=64 (2 mfma k-steps x 8 col-tiles).
__global__ __launch_bounds__(256) void proj_kernel(const float* __restrict__ x,
                                                   const unsigned short* __restrict__ Wg,
                                                   unsigned short* __restrict__ Y1,
                                                   float* __restrict__ Bs) {
    __shared__ unsigned short Wl[128 * 72];   // row stride 72 shorts (144B): 2-way bank alias = free
    const int t = threadIdx.x;

    // stage Wg (16 KB, coalesced dwordx4) into padded LDS
    for (int i = t; i < 1024; i += 256) {     // 16B chunk i: row=i>>3, seg=i&7
        int4 v = ((const int4*)Wg)[i];
        *((int4*)((char*)Wl + (i >> 3) * 144 + (i & 7) * 16)) = v;
    }
    __syncthreads();

    const int lane = t & 63;
    const int wv = t >> 6;
    const int m = lane & 15;          // row-within-tile for A; col-within-tile for C/D
    const int q = lane >> 4;          // quarter-wave
    const int rbase = blockIdx.x * 64 + wv * 16;

    // A-frags: lane reads 16B-contig chunks of its x row, cvt fp32->bf16
    const float* xr = x + (size_t)(rbase + m) * 64 + q * 8;
    f4 x0 = *(const f4*)(xr);         // k-step 0: k = q*8 .. q*8+7
    f4 x1 = *(const f4*)(xr + 4);
    f4 x2 = *(const f4*)(xr + 32);    // k-step 1
    f4 x3 = *(const f4*)(xr + 36);
    s8 A0, A1;
    A0[0]=f2bf(x0.x); A0[1]=f2bf(x0.y); A0[2]=f2bf(x0.z); A0[3]=f2bf(x0.w);
    A0[4]=f2bf(x1.x); A0[5]=f2bf(x1.y); A0[6]=f2bf(x1.z); A0[7]=f2bf(x1.w);
    A1[0]=f2bf(x2.x); A1[1]=f2bf(x2.y); A1[2]=f2bf(x2.z); A1[3]=f2bf(x2.w);
    A1[4]=f2bf(x3.x); A1[5]=f2bf(x3.y); A1[6]=f2bf(x3.z); A1[7]=f2bf(x3.w);

    f4 acc[8];
#pragma unroll
    for (int tt = 0; tt < 8; ++tt) acc[tt] = (f4)0.f;

#pragma unroll
    for (int s = 0; s < 2; ++s) {
        const s8 A = s ? A1 : A0;
#pragma unroll
        for (int tt = 0; tt < 8; ++tt) {
            // B-frag: B[n=16*tt+m][k=32*s + q*8 + j], 16B-aligned in padded LDS
            s8 b = *(const s8*)((const char*)Wl + (16 * tt + m) * 144 + s * 64 + q * 16);
            acc[tt] = __builtin_amdgcn_mfma_f32_16x16x32_bf16(A, b, acc[tt], 0, 0, 0);
        }
    }

    // C/D layout: col = 16*tt + m, row = rbase + q*4 + j   [m89-verified mapping]
    const int orow = rbase + q * 4;
#pragma unroll
    for (int tt = 0; tt < 4; ++tt) {          // cols 0..63 -> Y1 (bf16)
#pragma unroll
        for (int j = 0; j < 4; ++j)
            Y1[(size_t)(orow + j) * 64 + 16 * tt + m] = (unsigned short)f2bf(acc[tt][j]);
    }
#pragma unroll
    for (int tt = 4; tt < 8; ++tt) {          // cols 64..127 -> Bs (f32)
#pragma unroll
        for (int j = 0; j < 4; ++j)
            Bs[(size_t)(orow + j) * 64 + 16 * (tt - 4) + m] = acc[tt][j];
    }
}

// ---------------- Kernel 2: gather + max + LN + GELU ----------------
// 4 points/wave, 16 lanes/point, 4 ch/lane. XCD-pinned: batch bt -> dispatch idx ≡ bt (mod 8),
// so each XCD's L2 serves 2 batches = 2 MB of gather table.
__global__ __launch_bounds__(256) void gather_kernel(const unsigned short* __restrict__ Y1,
                                                     const float* __restrict__ Bs,
                                                     const int* __restrict__ ind,
                                                     const float* __restrict__ gamma,
                                                     const float* __restrict__ beta,
                                                     float* __restrict__ out) {
    const int lane = threadIdx.x & 63;
    const int wave = threadIdx.x >> 6;
    const int sub = lane & 15;          // channel group within point
    const int q = lane >> 4;            // point within wave
    const int bi = blockIdx.x;          // 8192 blocks
    const int bt = bi & 15;             // batch (pins XCD = bt % 8 under round-robin dispatch)
    const int jj = bi >> 4;             // tile within batch
    const int p = bt * N_ + jj * 16 + wave * 4 + q;
    const int bbase = bt * N_ * 64;

    int idxs[K_];
    const int4* ip = (const int4*)&ind[p * K_];   // 20*4B per point: 16B-aligned
#pragma unroll
    for (int v = 0; v < 5; ++v) {
        int4 iv = ip[v];
        idxs[4 * v + 0] = iv.x; idxs[4 * v + 1] = iv.y;
        idxs[4 * v + 2] = iv.z; idxs[4 * v + 3] = iv.w;
    }

    // issue all 20 gathers (128B L2-resident rows) before reducing: max MLP
    ushort4 rowv[K_];
#pragma unroll
    for (int k = 0; k < K_; ++k)
        rowv[k] = *(const ushort4*)(Y1 + bbase + idxs[k] * 64 + sub * 4);

    f4 m0 = (f4)(-INFINITY), m1 = (f4)(-INFINITY);
#pragma unroll
    for (int k = 0; k < K_; k += 2) {
        f4 f0 = bf4_to_f4(rowv[k]);
        f4 f1 = bf4_to_f4(rowv[k + 1]);
        m0.x = fmaxf(m0.x, f0.x); m0.y = fmaxf(m0.y, f0.y);
        m0.z = fmaxf(m0.z, f0.z); m0.w = fmaxf(m0.w, f0.w);
        m1.x = fmaxf(m1.x, f1.x); m1.y = fmaxf(m1.y, f1.y);
        m1.z = fmaxf(m1.z, f1.z); m1.w = fmaxf(m1.w, f1.w);
    }
    f4 m;
    m.x = fmaxf(m0.x, m1.x); m.y = fmaxf(m0.y, m1.y);
    m.z = fmaxf(m0.z, m1.z); m.w = fmaxf(m0.w, m1.w);

    f4 base = __builtin_nontemporal_load((const f4*)&Bs[(size_t)p * 64 + sub * 4]);
    f4 h = m + base;

    // LayerNorm over 64 channels = 4 comps x 16 lanes
    float s = h.x + h.y + h.z + h.w;
#pragma unroll
    for (int off = 8; off >= 1; off >>= 1) s += __shfl_xor(s, off, 64);
    const float mu = s * (1.0f / 64.0f);
    f4 dv = h - mu;
    float v2 = dv.x * dv.x + dv.y * dv.y + dv.z * dv.z + dv.w * dv.w;
#pragma unroll
    for (int off = 8; off >= 1; off >>= 1) v2 += __shfl_xor(v2, off, 64);
    const float rstd = rsqrtf(v2 * (1.0f / 64.0f) + 1e-5f);

    f4 g4 = *(const f4*)&gamma[sub * 4];
    f4 b4 = *(const f4*)&beta[sub * 4];
    f4 hn = dv * rstd * g4 + b4;

    f4 r;
    r.x = 0.5f * hn.x * (1.0f + erff(hn.x * 0.70710678f));
    r.y = 0.5f * hn.y * (1.0f + erff(hn.y * 0.70710678f));
    r.z = 0.5f * hn.z * (1.0f + erff(hn.z * 0.70710678f));
    r.w = 0.5f * hn.w * (1.0f + erff(hn.w * 0.70710678f));
    __builtin_nontemporal_store(r, (f4*)&out[(size_t)p * 64 + sub * 4]);
}

extern "C" void kernel_launch(void* const* d_in, const int* in_sizes, int n_in,
                              void* d_out, int out_size, void* d_ws, size_t ws_size,
                              hipStream_t stream) {
    const float* x     = (const float*)d_in[0];
    const int*   ind   = (const int*)d_in[1];
    const float* W     = (const float*)d_in[2];
    const float* gamma = (const float*)d_in[3];
    const float* beta  = (const float*)d_in[4];
    float* out = (float*)d_out;

    float* Bs = (float*)d_ws;                                               // 33.5 MB f32
    unsigned short* Y1 = (unsigned short*)((char*)d_ws + (size_t)NPTS * 64 * 4);   // 16.8 MB bf16
    unsigned short* Wg = (unsigned short*)((char*)d_ws + (size_t)NPTS * 64 * 6);   // 16 KB bf16

    prep_kernel<<<32, 256, 0, stream>>>(W, Wg);
    proj_kernel<<<NPTS / 64, 256, 0, stream>>>(x, Wg, Y1, Bs);
    gather_kernel<<<NPTS / 16, 256, 0, stream>>>(Y1, Bs, ind, gamma, beta, out);
}

// Round 6
// 131.684 us; speedup vs baseline: 2.0499x; 1.0564x over previous
//
#include <hip/hip_runtime.h>
#include <math.h>

// EdgeConv: B=16, N=8192, K=20, D=64
// h[b,n,k,o] = Y1[b,idx,o] + Bs[b,n,o];  out = GELU(LN(max_k h))
// Y1[p][o] = sum_d x[p][d]*W[o][d]          (bf16 table, gathered)
// Bs[p][o] = sum_d x[p][d]*(W[o][64+d]-W[o][d])   (bf16, streamed)
#define B_ 16
#define N_ 8192
#define K_ 20
#define NPTS (B_ * N_)   // 131072

typedef __attribute__((ext_vector_type(4))) float f4;
typedef __attribute__((ext_vector_type(8))) short s8;          // 8 x bf16 MFMA fragment
typedef __attribute__((ext_vector_type(4))) unsigned int u4;   // 16B untyped
typedef __attribute__((ext_vector_type(4))) unsigned short us4;// 8B packed bf16

__device__ __forceinline__ unsigned short f2bf(float f) {
    union { float f; unsigned u; } v; v.f = f;
    return (unsigned short)((v.u + 0x7FFFu + ((v.u >> 16) & 1u)) >> 16);   // RNE
}
__device__ __forceinline__ float bfhi(unsigned w) { return __uint_as_float(w & 0xFFFF0000u); }
__device__ __forceinline__ float bflo(unsigned w) { return __uint_as_float(w << 16); }

// ---------------- Kernel 0: combined W in bf16 ----------------
// Wg[j][d], j<64 -> W[j][d] ; j>=64 -> W[j-64][64+d]-W[j-64][d]
__global__ __launch_bounds__(256) void prep_kernel(const float* __restrict__ W,
                                                   unsigned short* __restrict__ Wg) {
    const int i = blockIdx.x * 256 + threadIdx.x;   // 8192 elems
    const int j = i >> 6, d = i & 63;
    const float v = (j < 64) ? W[j * 128 + d]
                             : (W[(j - 64) * 128 + 64 + d] - W[(j - 64) * 128 + d]);
    Wg[i] = f2bf(v);
}

// ---------------- Kernel 1: projections via MFMA (A=W, B=x) ----------------
// Each wave: 16 points x 128 outputs. D-layout: row(o-in-tile)=q*4+j, col(point)=m.
// => lane's 4 acc regs are 4 CONSECUTIVE output channels -> packed 8B stores.
__global__ __launch_bounds__(256) void proj_kernel(const float* __restrict__ x,
                                                   const unsigned short* __restrict__ Wg,
                                                   unsigned short* __restrict__ Y1,
                                                   unsigned short* __restrict__ Bs) {
    __shared__ unsigned short Wl[128 * 72];   // row stride 144B: 2-way bank alias = free
    const int t = threadIdx.x;

    for (int i = t; i < 1024; i += 256) {     // stage 16KB Wg, coalesced dwordx4
        u4 v = ((const u4*)Wg)[i];
        *((u4*)((char*)Wl + (i >> 3) * 144 + (i & 7) * 16)) = v;
    }
    __syncthreads();

    const int lane = t & 63;
    const int wv = t >> 6;
    const int m = lane & 15;          // point-within-tile (B idx) AND W-row-within-tile (A idx)
    const int q = lane >> 4;
    const int pbase = blockIdx.x * 64 + wv * 16;

    // B-frag (x): lane reads 16B-contig chunks of its point's row
    const float* xr = x + (size_t)(pbase + m) * 64 + q * 8;
    f4 x0 = *(const f4*)(xr);
    f4 x1 = *(const f4*)(xr + 4);
    f4 x2 = *(const f4*)(xr + 32);
    f4 x3 = *(const f4*)(xr + 36);
    s8 X0, X1;
    X0[0]=(short)f2bf(x0.x); X0[1]=(short)f2bf(x0.y); X0[2]=(short)f2bf(x0.z); X0[3]=(short)f2bf(x0.w);
    X0[4]=(short)f2bf(x1.x); X0[5]=(short)f2bf(x1.y); X0[6]=(short)f2bf(x1.z); X0[7]=(short)f2bf(x1.w);
    X1[0]=(short)f2bf(x2.x); X1[1]=(short)f2bf(x2.y); X1[2]=(short)f2bf(x2.z); X1[3]=(short)f2bf(x2.w);
    X1[4]=(short)f2bf(x3.x); X1[5]=(short)f2bf(x3.y); X1[6]=(short)f2bf(x3.z); X1[7]=(short)f2bf(x3.w);

    f4 acc[8];
#pragma unroll
    for (int tt = 0; tt < 8; ++tt) acc[tt] = (f4)0.f;

#pragma unroll
    for (int s = 0; s < 2; ++s) {
        const s8 X = s ? X1 : X0;
#pragma unroll
        for (int tt = 0; tt < 8; ++tt) {
            // A-frag (W): A[m][k=s*32+q*8+j], 16B-aligned in padded LDS
            s8 w = *(const s8*)((const char*)Wl + (16 * tt + m) * 144 + s * 64 + q * 16);
            acc[tt] = __builtin_amdgcn_mfma_f32_16x16x32_bf16(w, X, acc[tt], 0, 0, 0);
        }
    }

    // D: o = 16*tt + q*4 + j, point = pbase + m  -> packed us4 (8B) stores
    const size_t prow = (size_t)(pbase + m) * 64;
#pragma unroll
    for (int tt = 0; tt < 4; ++tt) {
        us4 u;
        u.x = f2bf(acc[tt][0]); u.y = f2bf(acc[tt][1]);
        u.z = f2bf(acc[tt][2]); u.w = f2bf(acc[tt][3]);
        *(us4*)&Y1[prow + tt * 16 + q * 4] = u;
    }
#pragma unroll
    for (int tt = 4; tt < 8; ++tt) {
        us4 u;
        u.x = f2bf(acc[tt][0]); u.y = f2bf(acc[tt][1]);
        u.z = f2bf(acc[tt][2]); u.w = f2bf(acc[tt][3]);
        *(us4*)&Bs[prow + (tt - 4) * 16 + q * 4] = u;
    }
}

// ---------------- Kernel 2: gather + max + LN + GELU ----------------
// 8 points/wave, 8 lanes/point, 8 ch/lane: 16B gathers (half the VMEM instrs).
// XCD-pinned: batch bt = blockIdx&15 -> XCD bt%8 caches 2 batches (2.1MB bf16 table).
__global__ __launch_bounds__(256) void gather_kernel(const unsigned short* __restrict__ Y1,
                                                     const unsigned short* __restrict__ Bs,
                                                     const int* __restrict__ ind,
                                                     const float* __restrict__ gamma,
                                                     const float* __restrict__ beta,
                                                     float* __restrict__ out) {
    const int lane = threadIdx.x & 63;
    const int wave = threadIdx.x >> 6;
    const int sub = lane & 7;            // channel group (8 ch)
    const int q = lane >> 3;             // point within wave
    const int bi = blockIdx.x;           // 4096 blocks
    const int bt = bi & 15;
    const int jj = bi >> 4;
    const int p = bt * N_ + jj * 32 + wave * 8 + q;
    const int bbase = bt * N_ * 64;

    int idxs[K_];
    const int4* ip = (const int4*)&ind[p * K_];   // 80B/point, 16B-aligned
#pragma unroll
    for (int v = 0; v < 5; ++v) {
        int4 iv = ip[v];
        idxs[4 * v + 0] = iv.x; idxs[4 * v + 1] = iv.y;
        idxs[4 * v + 2] = iv.z; idxs[4 * v + 3] = iv.w;
    }

    f4 ma = (f4)(-INFINITY), mb = (f4)(-INFINITY);
#pragma unroll
    for (int r = 0; r < 2; ++r) {        // 2 rounds x 10 outstanding 16B gathers
        u4 rv[10];
#pragma unroll
        for (int k = 0; k < 10; ++k)
            rv[k] = *(const u4*)(Y1 + bbase + idxs[r * 10 + k] * 64 + sub * 8);
#pragma unroll
        for (int k = 0; k < 10; ++k) {
            ma.x = fmaxf(ma.x, bflo(rv[k].x)); ma.y = fmaxf(ma.y, bfhi(rv[k].x));
            ma.z = fmaxf(ma.z, bflo(rv[k].y)); ma.w = fmaxf(ma.w, bfhi(rv[k].y));
            mb.x = fmaxf(mb.x, bflo(rv[k].z)); mb.y = fmaxf(mb.y, bfhi(rv[k].z));
            mb.z = fmaxf(mb.z, bflo(rv[k].w)); mb.w = fmaxf(mb.w, bfhi(rv[k].w));
        }
    }

    u4 bsv = __builtin_nontemporal_load((const u4*)(Bs + (size_t)p * 64 + sub * 8));
    f4 ha, hb;
    ha.x = ma.x + bflo(bsv.x); ha.y = ma.y + bfhi(bsv.x);
    ha.z = ma.z + bflo(bsv.y); ha.w = ma.w + bfhi(bsv.y);
    hb.x = mb.x + bflo(bsv.z); hb.y = mb.y + bfhi(bsv.z);
    hb.z = mb.z + bflo(bsv.w); hb.w = mb.w + bfhi(bsv.w);

    // LayerNorm over 64 ch = 8 comps x 8 lanes (xor masks 1,2,4 stay in-group)
    float s = ha.x + ha.y + ha.z + ha.w + hb.x + hb.y + hb.z + hb.w;
#pragma unroll
    for (int off = 4; off >= 1; off >>= 1) s += __shfl_xor(s, off, 64);
    const float mu = s * (1.0f / 64.0f);
    f4 da = ha - mu, db = hb - mu;
    float v2 = da.x * da.x + da.y * da.y + da.z * da.z + da.w * da.w
             + db.x * db.x + db.y * db.y + db.z * db.z + db.w * db.w;
#pragma unroll
    for (int off = 4; off >= 1; off >>= 1) v2 += __shfl_xor(v2, off, 64);
    const float rstd = rsqrtf(v2 * (1.0f / 64.0f) + 1e-5f);

    const f4 g0 = *(const f4*)&gamma[sub * 8];
    const f4 g1 = *(const f4*)&gamma[sub * 8 + 4];
    const f4 b0 = *(const f4*)&beta[sub * 8];
    const f4 b1 = *(const f4*)&beta[sub * 8 + 4];
    f4 na = da * rstd * g0 + b0;
    f4 nb = db * rstd * g1 + b1;

    f4 r0, r1;
    r0.x = 0.5f * na.x * (1.0f + erff(na.x * 0.70710678f));
    r0.y = 0.5f * na.y * (1.0f + erff(na.y * 0.70710678f));
    r0.z = 0.5f * na.z * (1.0f + erff(na.z * 0.70710678f));
    r0.w = 0.5f * na.w * (1.0f + erff(na.w * 0.70710678f));
    r1.x = 0.5f * nb.x * (1.0f + erff(nb.x * 0.70710678f));
    r1.y = 0.5f * nb.y * (1.0f + erff(nb.y * 0.70710678f));
    r1.z = 0.5f * nb.z * (1.0f + erff(nb.z * 0.70710678f));
    r1.w = 0.5f * nb.w * (1.0f + erff(nb.w * 0.70710678f));
    float* op = &out[(size_t)p * 64 + sub * 8];
    __builtin_nontemporal_store(r0, (f4*)op);
    __builtin_nontemporal_store(r1, (f4*)(op + 4));
}

extern "C" void kernel_launch(void* const* d_in, const int* in_sizes, int n_in,
                              void* d_out, int out_size, void* d_ws, size_t ws_size,
                              hipStream_t stream) {
    const float* x     = (const float*)d_in[0];
    const int*   ind   = (const int*)d_in[1];
    const float* W     = (const float*)d_in[2];
    const float* gamma = (const float*)d_in[3];
    const float* beta  = (const float*)d_in[4];
    float* out = (float*)d_out;

    unsigned short* Bs = (unsigned short*)d_ws;          // 16.8 MB bf16
    unsigned short* Y1 = Bs + (size_t)NPTS * 64;         // 16.8 MB bf16
    unsigned short* Wg = Y1 + (size_t)NPTS * 64;         // 16 KB bf16

    prep_kernel<<<32, 256, 0, stream>>>(W, Wg);
    proj_kernel<<<NPTS / 64, 256, 0, stream>>>(x, Wg, Y1, Bs);
    gather_kernel<<<NPTS / 32, 256, 0, stream>>>(Y1, Bs, ind, gamma, beta, out);
}